// Round 6
// baseline (152.457 us; speedup 1.0000x reference)
//
#include <hip/hip_runtime.h>
#include <math.h>

// Problem shape (fixed by setup_inputs): B=8192 rows, D=2048 cols, fp32.
static constexpr int Dn = 2048;
static constexpr int Bn = 8192;
static constexpr int NBLK  = 1024;       // 256 thr each -> 4096 waves, 4 waves/SIMD
static constexpr int NWAVE = NBLK * 4;   // 2 rows per wave

typedef float f4 __attribute__((ext_vector_type(4)));

__device__ __forceinline__ float dot4(f4 a, f4 b) {
    return a.x * b.x + a.y * b.y + a.z * b.z + a.w * b.w;
}

// Single fused kernel (last-block-done finisher).
// Per wave (as R5, which matched R2's best):
//  - issue BOTH rows' 8+8 dwordx4 loads first (16 outstanding HBM loads/lane)
//  - build normalized anchor a = embed[0]/max(||.||,1e-12) in registers while
//    the row loads fly (8 KB L2-hot broadcast)
//  - in-lane dots, then 4 independent 6-step __shfl_xor butterflies
//  - lane 0 forms fp64 partials (j != 0 masked)
// Per block:
//  - LDS-reduce the 4 wave triples -> one (sE,sL,sN) per block -> part[] (SoA)
//  - __threadfence + device atomicAdd; the last block re-reduces the 1024
//    L2-hot triples and computes the final scalar. No second kernel launch.
__global__ __launch_bounds__(256) void k_fused(const float* __restrict__ embed,
                                               const float* __restrict__ ee,
                                               const float* __restrict__ labels,
                                               double* __restrict__ part,
                                               unsigned int* __restrict__ done,
                                               float* __restrict__ out) {
    __shared__ double rE[4], rL[4], rN[4];
    __shared__ int isLast;
    const int t    = threadIdx.x;
    const int lane = t & 63;
    const int w    = t >> 6;
    const int blk  = blockIdx.x;
    const int wv   = (blk << 2) | w;     // global wave id
    const int j0   = wv;                 // row pair
    const int j1   = wv + NWAVE;

    // ---- both rows' loads issued first: 16 dwordx4 in flight per lane ----
    const f4* r0 = reinterpret_cast<const f4*>(ee + (size_t)j0 * Dn);
    const f4* r1 = reinterpret_cast<const f4*>(ee + (size_t)j1 * Dn);
    f4 x0[8], x1[8];
#pragma unroll
    for (int s = 0; s < 8; ++s) x0[s] = r0[(s << 6) + lane];
#pragma unroll
    for (int s = 0; s < 8; ++s) x1[s] = r1[(s << 6) + lane];

    // labels early too (lane 0 only consumes them)
    float lb0 = 0.f, lb1 = 0.f;
    if (lane == 0) { lb0 = labels[j0]; lb1 = labels[j1]; }

    // ---- anchor fragment (overlaps the row loads) ----
    const f4* e0 = reinterpret_cast<const f4*>(embed);
    f4 av[8];
    float ss = 0.f;
#pragma unroll
    for (int s = 0; s < 8; ++s) {
        av[s] = e0[(s << 6) + lane];
        ss += dot4(av[s], av[s]);
    }
#pragma unroll
    for (int o = 32; o > 0; o >>= 1) ss += __shfl_xor(ss, o, 64);
    const float inv = 1.0f / fmaxf(sqrtf(ss), 1e-12f);

    float ssa = 0.f;
#pragma unroll
    for (int s = 0; s < 8; ++s) {
        av[s] *= inv;
        ssa += dot4(av[s], av[s]);
    }
#pragma unroll
    for (int o = 32; o > 0; o >>= 1) ssa += __shfl_xor(ssa, o, 64);
    const float na = fmaxf(sqrtf(ssa), 1e-6f);  // = max(||a||, 1e-6), cos eps

    // ---- in-lane dots for both rows ----
    float dt0 = 0.f, sr0 = 0.f, dt1 = 0.f, sr1 = 0.f;
#pragma unroll
    for (int s = 0; s < 8; ++s) {
        dt0 += dot4(x0[s], av[s]);
        sr0 += dot4(x0[s], x0[s]);
        dt1 += dot4(x1[s], av[s]);
        sr1 += dot4(x1[s], x1[s]);
    }

    // ---- four independent butterfly chains (dual-issue pairs) ----
#pragma unroll
    for (int o = 32; o > 0; o >>= 1) {
        dt0 += __shfl_xor(dt0, o, 64);
        dt1 += __shfl_xor(dt1, o, 64);
        sr0 += __shfl_xor(sr0, o, 64);
        sr1 += __shfl_xor(sr1, o, 64);
    }

    // ---- wave triple -> LDS ----
    if (lane == 0) {
        double sE = 0.0, sL = 0.0, sN = 0.0;
        if (j0 != 0) {  // mask: exclude j == i == 0 (j0 == 0 only for wave 0)
            const float nb  = fmaxf(sqrtf(sr0), 1e-6f);
            const float neg = -10.0f * dt0 / (na * nb);  // -cos/T, T = 0.1
            sE += (double)expf(neg);
            sL += (double)lb0;
            sN += (double)lb0 * (double)neg;
        }
        {
            const float nb  = fmaxf(sqrtf(sr1), 1e-6f);
            const float neg = -10.0f * dt1 / (na * nb);
            sE += (double)expf(neg);
            sL += (double)lb1;
            sN += (double)lb1 * (double)neg;
        }
        rE[w] = sE; rL[w] = sL; rN[w] = sN;
    }
    __syncthreads();

    // ---- block triple -> global, then last-block handoff ----
    if (t == 0) {
        part[blk]            = rE[0] + rE[1] + rE[2] + rE[3];
        part[NBLK + blk]     = rL[0] + rL[1] + rL[2] + rL[3];
        part[2 * NBLK + blk] = rN[0] + rN[1] + rN[2] + rN[3];
        __threadfence();                       // release: part[] visible device-wide
        const unsigned int old = atomicAdd(done, 1u);
        isLast = (old == (unsigned int)(NBLK - 1));
    }
    __syncthreads();
    if (!isLast) return;

    // ---- finisher (one block, L2-hot 24 KB) ----
    __threadfence();                           // acquire side
    double sE = 0.0, sL = 0.0, sN = 0.0;
    for (int i = t; i < NBLK; i += 256) {
        sE += part[i];
        sL += part[NBLK + i];
        sN += part[2 * NBLK + i];
    }
#pragma unroll
    for (int o = 32; o > 0; o >>= 1) {
        sE += __shfl_down(sE, o, 64);
        sL += __shfl_down(sL, o, 64);
        sN += __shfl_down(sN, o, 64);
    }
    if (lane == 0) { rE[w] = sE; rL[w] = sL; rN[w] = sN; }
    __syncthreads();
    if (t == 0) {
        const double E0 = 1e-12 + rE[0] + rE[1] + rE[2] + rE[3];
        const double S2 = rL[0] + rL[1] + rL[2] + rL[3];
        const double S3 = rN[0] + rN[1] + rN[2] + rN[3];
        const double l0 = (double)labels[0];
        const double C0 = 1e-12 + l0 * S2;
        const double L0 = -(l0 / C0) * (S3 - log(E0) * S2);
        out[0] = (float)(L0 / (double)Bn);
    }
}

extern "C" void kernel_launch(void* const* d_in, const int* in_sizes, int n_in,
                              void* d_out, int out_size, void* d_ws, size_t ws_size,
                              hipStream_t stream) {
    const float* embed  = (const float*)d_in[0];  // [B, D] — only row 0 used
    const float* ee     = (const float*)d_in[1];  // [B, D]
    const float* labels = (const float*)d_in[2];  // [B]
    float* out = (float*)d_out;

    // ws layout: part = 3*NBLK doubles (24 KB), then the 4-byte done counter.
    double* part = (double*)d_ws;
    unsigned int* done = (unsigned int*)((char*)d_ws + 3 * NBLK * sizeof(double));

    // Counter must start at 0 every call (ws is 0xAA-poisoned before timed
    // launches, undefined on the correctness call) — tiny async memset is
    // graph-capturable.
    hipMemsetAsync(done, 0, sizeof(unsigned int), stream);
    k_fused<<<NBLK, 256, 0, stream>>>(embed, ee, labels, part, done, out);
}

// Round 7
// 128.875 us; speedup vs baseline: 1.1830x; 1.1830x over previous
//
#include <hip/hip_runtime.h>
#include <math.h>

// Problem shape (fixed by setup_inputs): B=8192 rows, D=2048 cols, fp32.
static constexpr int Dn = 2048;
static constexpr int Bn = 8192;
static constexpr int NBLK  = 1024;       // 256 thr each -> 4096 waves
static constexpr int NWAVE = NBLK * 4;   // 2 rows per wave

typedef float f4 __attribute__((ext_vector_type(4)));

__device__ __forceinline__ float dot4(f4 a, f4 b) {
    return a.x * b.x + a.y * b.y + a.z * b.z + a.w * b.w;
}

// Fused main kernel. Per wave:
//  - issue BOTH rows' 8+8 dwordx4 loads first (16 outstanding HBM loads/lane)
//  - while they fly, build the normalized anchor a = embed[0]/max(||.||,1e-12)
//  - in-lane dots, then 4 independent 6-step __shfl_xor butterflies
//  - lane 0 writes fp64 partials (j != 0 masked), one SoA triple per wave.
//
// __launch_bounds__(256, 4): R6's rocprof showed the compiler allocating only
// 64 VGPRs for this body (8-waves/EU heuristic), which cannot hold the
// av[8]+x0[8]+x1[8] = 96-reg live set -> spills/sunk loads -> 44-65 us at 8%
// of HBM peak. min-4-waves/EU caps at 128 VGPRs: live set fits, load batch
// stays batched, 16 waves/CU still hides ~900-cyc HBM latency.
__global__ __launch_bounds__(256, 4) void k_main(const float* __restrict__ embed,
                                                 const float* __restrict__ ee,
                                                 const float* __restrict__ labels,
                                                 double* __restrict__ part) {
    const int t    = threadIdx.x;
    const int lane = t & 63;
    const int wv   = ((int)blockIdx.x << 2) | (t >> 6);  // global wave id
    const int j0   = wv;                                  // row pair
    const int j1   = wv + NWAVE;

    // ---- both rows' loads issued first: 16 dwordx4 in flight per lane ----
    const f4* r0 = reinterpret_cast<const f4*>(ee + (size_t)j0 * Dn);
    const f4* r1 = reinterpret_cast<const f4*>(ee + (size_t)j1 * Dn);
    f4 x0[8], x1[8];
#pragma unroll
    for (int s = 0; s < 8; ++s) x0[s] = r0[(s << 6) + lane];
#pragma unroll
    for (int s = 0; s < 8; ++s) x1[s] = r1[(s << 6) + lane];

    // labels early too (lane 0 only consumes them)
    float lb0 = 0.f, lb1 = 0.f;
    if (lane == 0) { lb0 = labels[j0]; lb1 = labels[j1]; }

    // ---- anchor fragment (overlaps the row loads) ----
    const f4* e0 = reinterpret_cast<const f4*>(embed);
    f4 av[8];
    float ss = 0.f;
#pragma unroll
    for (int s = 0; s < 8; ++s) {
        av[s] = e0[(s << 6) + lane];
        ss += dot4(av[s], av[s]);
    }
#pragma unroll
    for (int o = 32; o > 0; o >>= 1) ss += __shfl_xor(ss, o, 64);
    const float inv = 1.0f / fmaxf(sqrtf(ss), 1e-12f);

    float ssa = 0.f;
#pragma unroll
    for (int s = 0; s < 8; ++s) {
        av[s] *= inv;
        ssa += dot4(av[s], av[s]);
    }
#pragma unroll
    for (int o = 32; o > 0; o >>= 1) ssa += __shfl_xor(ssa, o, 64);
    const float na = fmaxf(sqrtf(ssa), 1e-6f);  // = max(||a||, 1e-6), cos eps

    // ---- in-lane dots for both rows ----
    float dt0 = 0.f, sr0 = 0.f, dt1 = 0.f, sr1 = 0.f;
#pragma unroll
    for (int s = 0; s < 8; ++s) {
        dt0 += dot4(x0[s], av[s]);
        sr0 += dot4(x0[s], x0[s]);
        dt1 += dot4(x1[s], av[s]);
        sr1 += dot4(x1[s], x1[s]);
    }

    // ---- four independent butterfly chains (dual-issue pairs) ----
#pragma unroll
    for (int o = 32; o > 0; o >>= 1) {
        dt0 += __shfl_xor(dt0, o, 64);
        dt1 += __shfl_xor(dt1, o, 64);
        sr0 += __shfl_xor(sr0, o, 64);
        sr1 += __shfl_xor(sr1, o, 64);
    }

    if (lane == 0) {
        double sE = 0.0, sL = 0.0, sN = 0.0;
        if (j0 != 0) {  // mask: exclude j == i == 0 (j0 == 0 only for wave 0)
            const float nb  = fmaxf(sqrtf(sr0), 1e-6f);
            const float neg = -10.0f * dt0 / (na * nb);  // -cos/T, T = 0.1
            sE += (double)expf(neg);
            sL += (double)lb0;
            sN += (double)lb0 * (double)neg;
        }
        {
            const float nb  = fmaxf(sqrtf(sr1), 1e-6f);
            const float neg = -10.0f * dt1 / (na * nb);
            sE += (double)expf(neg);
            sL += (double)lb1;
            sN += (double)lb1 * (double)neg;
        }
        part[wv]             = sE;   // SoA for coalesced finisher reads
        part[NWAVE + wv]     = sL;
        part[2 * NWAVE + wv] = sN;
    }
}

// Finisher: 1 block, fp64 reduce of 4096 wave-partials, then the scalar math:
//   E0 = 1e-12 + SE;  C0 = 1e-12 + l0*SL
//   L0 = -(l0/C0) * (SN - log(E0)*SL);  out = L0/B
__global__ __launch_bounds__(256) void k_final(const double* __restrict__ part,
                                               const float* __restrict__ labels,
                                               float* __restrict__ out) {
    __shared__ double rE[4], rL[4], rN[4];
    const int t = threadIdx.x;
    const int lane = t & 63, wave = t >> 6;

    double sE = 0.0, sL = 0.0, sN = 0.0;
    for (int i = t; i < NWAVE; i += 256) {
        sE += part[i];
        sL += part[NWAVE + i];
        sN += part[2 * NWAVE + i];
    }
#pragma unroll
    for (int o = 32; o > 0; o >>= 1) {
        sE += __shfl_down(sE, o, 64);
        sL += __shfl_down(sL, o, 64);
        sN += __shfl_down(sN, o, 64);
    }
    if (lane == 0) { rE[wave] = sE; rL[wave] = sL; rN[wave] = sN; }
    __syncthreads();
    if (t == 0) {
        const double E0 = 1e-12 + rE[0] + rE[1] + rE[2] + rE[3];
        const double S2 = rL[0] + rL[1] + rL[2] + rL[3];
        const double S3 = rN[0] + rN[1] + rN[2] + rN[3];
        const double l0 = (double)labels[0];
        const double C0 = 1e-12 + l0 * S2;
        const double L0 = -(l0 / C0) * (S3 - log(E0) * S2);
        out[0] = (float)(L0 / (double)Bn);
    }
}

extern "C" void kernel_launch(void* const* d_in, const int* in_sizes, int n_in,
                              void* d_out, int out_size, void* d_ws, size_t ws_size,
                              hipStream_t stream) {
    const float* embed  = (const float*)d_in[0];  // [B, D] — only row 0 used
    const float* ee     = (const float*)d_in[1];  // [B, D]
    const float* labels = (const float*)d_in[2];  // [B]
    float* out = (float*)d_out;

    double* part = (double*)d_ws;  // 3 * NWAVE doubles = 96 KB, fully overwritten

    k_main<<<NBLK, 256, 0, stream>>>(embed, ee, labels, part);
    k_final<<<1, 256, 0, stream>>>(part, labels, out);
}

// Round 8
// 126.168 us; speedup vs baseline: 1.2084x; 1.0215x over previous
//
#include <hip/hip_runtime.h>
#include <math.h>

// Problem shape (fixed by setup_inputs): B=8192 rows, D=2048 cols, fp32.
static constexpr int Dn = 2048;
static constexpr int Bn = 8192;
static constexpr int NBLK  = 1024;       // 256 thr each -> 4096 waves
static constexpr int NWAVE = NBLK * 4;   // 2 rows per wave

typedef float f4 __attribute__((ext_vector_type(4)));

__device__ __forceinline__ float dot4(f4 a, f4 b) {
    return a.x * b.x + a.y * b.y + a.z * b.z + a.w * b.w;
}

// Fused main kernel. Per wave:
//  - issue BOTH rows' 8+8 dwordx4 loads first (16 outstanding HBM loads/lane)
//  - anchor kept UNNORMALIZED in registers: dt_raw = ee.e0 and the anchor's
//    own norm butterfly run as independent chains; inv folds in at the lane-0
//    epilogue (neg = -10*dt_raw*inv/(na*nb), na = max(sqrt(ss)*inv,1e-6)).
//    This deletes a 6-shuffle dependent chain + 8 VALU from the critical path.
//  - 5 independent butterflies total (ss, dt0, dt1, sr0, sr1) -> dual-issue.
//  - block-level LDS reduction -> ONE fp64 triple per block (24 KB total).
// __launch_bounds__(256,4): cap 128 VGPR so the 24-reg f4 live set fits
// (R6 showed the 8-wave/EU default allocates 64 VGPR -> spills -> 44+ us).
__global__ __launch_bounds__(256, 4) void k_main(const float* __restrict__ embed,
                                                 const float* __restrict__ ee,
                                                 const float* __restrict__ labels,
                                                 double* __restrict__ part) {
    __shared__ double bE[4], bL[4], bN[4];
    const int t    = threadIdx.x;
    const int lane = t & 63;
    const int w    = t >> 6;
    const int wv   = ((int)blockIdx.x << 2) | w;  // global wave id
    const int j0   = wv;                          // row pair
    const int j1   = wv + NWAVE;

    // ---- both rows' loads issued first: 16 dwordx4 in flight per lane ----
    const f4* r0 = reinterpret_cast<const f4*>(ee + (size_t)j0 * Dn);
    const f4* r1 = reinterpret_cast<const f4*>(ee + (size_t)j1 * Dn);
    f4 x0[8], x1[8];
#pragma unroll
    for (int s = 0; s < 8; ++s) x0[s] = r0[(s << 6) + lane];
#pragma unroll
    for (int s = 0; s < 8; ++s) x1[s] = r1[(s << 6) + lane];

    // labels early too (lane 0 only consumes them)
    float lb0 = 0.f, lb1 = 0.f;
    if (lane == 0) { lb0 = labels[j0]; lb1 = labels[j1]; }

    // ---- raw anchor fragment (L2-hot broadcast; no normalization) ----
    const f4* e0 = reinterpret_cast<const f4*>(embed);
    f4 av[8];
    float ss = 0.f;
#pragma unroll
    for (int s = 0; s < 8; ++s) {
        av[s] = e0[(s << 6) + lane];
        ss += dot4(av[s], av[s]);
    }

    // ---- in-lane dots for both rows (raw anchor) ----
    float dt0 = 0.f, sr0 = 0.f, dt1 = 0.f, sr1 = 0.f;
#pragma unroll
    for (int s = 0; s < 8; ++s) {
        dt0 += dot4(x0[s], av[s]);
        sr0 += dot4(x0[s], x0[s]);
        dt1 += dot4(x1[s], av[s]);
        sr1 += dot4(x1[s], x1[s]);
    }

    // ---- five independent butterfly chains (dual-issue) ----
#pragma unroll
    for (int o = 32; o > 0; o >>= 1) {
        ss  += __shfl_xor(ss,  o, 64);
        dt0 += __shfl_xor(dt0, o, 64);
        dt1 += __shfl_xor(dt1, o, 64);
        sr0 += __shfl_xor(sr0, o, 64);
        sr1 += __shfl_xor(sr1, o, 64);
    }

    // ---- wave triple -> LDS ----
    if (lane == 0) {
        const float nrm = sqrtf(ss);
        const float inv = 1.0f / fmaxf(nrm, 1e-12f);      // F.normalize eps
        const float na  = fmaxf(nrm * inv, 1e-6f);        // = max(||a||,1e-6) ~ 1
        const float sc  = -10.0f * inv / na;              // folds 1/T and inv
        double sE = 0.0, sL = 0.0, sN = 0.0;
        if (j0 != 0) {  // mask: exclude j == i == 0 (j0 == 0 only for wave 0)
            const float neg = sc * dt0 / fmaxf(sqrtf(sr0), 1e-6f);
            sE += (double)expf(neg);
            sL += (double)lb0;
            sN += (double)lb0 * (double)neg;
        }
        {
            const float neg = sc * dt1 / fmaxf(sqrtf(sr1), 1e-6f);
            sE += (double)expf(neg);
            sL += (double)lb1;
            sN += (double)lb1 * (double)neg;
        }
        bE[w] = sE; bL[w] = sL; bN[w] = sN;
    }
    __syncthreads();

    // ---- block triple -> global (SoA; one coalescable triple per block) ----
    if (t == 0) {
        part[blockIdx.x]            = bE[0] + bE[1] + bE[2] + bE[3];
        part[NBLK + blockIdx.x]     = bL[0] + bL[1] + bL[2] + bL[3];
        part[2 * NBLK + blockIdx.x] = bN[0] + bN[1] + bN[2] + bN[3];
    }
}

// Finisher: 1 block, fp64 reduce of 1024 block-partials (24 KB, L2-hot):
//   E0 = 1e-12 + SE;  C0 = 1e-12 + l0*SL
//   L0 = -(l0/C0) * (SN - log(E0)*SL);  out = L0/B
__global__ __launch_bounds__(256) void k_final(const double* __restrict__ part,
                                               const float* __restrict__ labels,
                                               float* __restrict__ out) {
    __shared__ double rE[4], rL[4], rN[4];
    const int t = threadIdx.x;
    const int lane = t & 63, wave = t >> 6;

    double sE = 0.0, sL = 0.0, sN = 0.0;
    for (int i = t; i < NBLK; i += 256) {
        sE += part[i];
        sL += part[NBLK + i];
        sN += part[2 * NBLK + i];
    }
#pragma unroll
    for (int o = 32; o > 0; o >>= 1) {
        sE += __shfl_down(sE, o, 64);
        sL += __shfl_down(sL, o, 64);
        sN += __shfl_down(sN, o, 64);
    }
    if (lane == 0) { rE[wave] = sE; rL[wave] = sL; rN[wave] = sN; }
    __syncthreads();
    if (t == 0) {
        const double E0 = 1e-12 + rE[0] + rE[1] + rE[2] + rE[3];
        const double S2 = rL[0] + rL[1] + rL[2] + rL[3];
        const double S3 = rN[0] + rN[1] + rN[2] + rN[3];
        const double l0 = (double)labels[0];
        const double C0 = 1e-12 + l0 * S2;
        const double L0 = -(l0 / C0) * (S3 - log(E0) * S2);
        out[0] = (float)(L0 / (double)Bn);
    }
}

extern "C" void kernel_launch(void* const* d_in, const int* in_sizes, int n_in,
                              void* d_out, int out_size, void* d_ws, size_t ws_size,
                              hipStream_t stream) {
    const float* embed  = (const float*)d_in[0];  // [B, D] — only row 0 used
    const float* ee     = (const float*)d_in[1];  // [B, D]
    const float* labels = (const float*)d_in[2];  // [B]
    float* out = (float*)d_out;

    double* part = (double*)d_ws;  // 3 * NBLK doubles = 24 KB, fully overwritten

    k_main<<<NBLK, 256, 0, stream>>>(embed, ee, labels, part);
    k_final<<<1, 256, 0, stream>>>(part, labels, out);
}